// Round 23
// baseline (4949.441 us; speedup 1.0000x reference)
//
#include <hip/hip_runtime.h>
#include <hip/hip_bf16.h>
#include <stdint.h>

#define DEV __device__ __forceinline__
typedef unsigned short u16;
typedef unsigned int   u32;
typedef unsigned long long u64;

static constexpr int SS = 256;   // src len
static constexpr int TT = 64;    // tgt len
static constexpr int EE = 256;   // embed dim
static constexpr int HH = 512;   // hidden
static constexpr int G3 = 1536;  // 3*H
static constexpr int VV = 32000; // vocab
static constexpr int HP  = 516;  // padded f32 LDS row (h tiles)
static constexpr int WPE = 516;  // padded f32 weight row (encoder)
static constexpr int WPD = 520;  // padded u16 weight row (decoder)
static constexpr int CP8 = 520;  // padded u16 ctx row (decoder)

using frag   = __attribute__((ext_vector_type(8))) short;  // 8 bf16
using f32x4v = __attribute__((ext_vector_type(4))) float;  // MFMA acc

// ---------- helpers ----------
DEV float blo(u32 u){ union{u32 i; float f;} x; x.i = u << 16;         return x.f; }
DEV float bhi(u32 u){ union{u32 i; float f;} x; x.i = u & 0xffff0000u; return x.f; }
DEV float bf2f(u16 u){ union{u32 i; float f;} x; x.i = ((u32)u) << 16; return x.f; }
DEV u16 f2bf(float f){ union{float f; u32 u;} v; v.f = f;
  u32 r = v.u + 0x7fffu + ((v.u >> 16) & 1u); return (u16)(r >> 16); }
DEV float sigf (float x){ return 1.0f / (1.0f + __expf(-x)); }
DEV float tanh_(float x){ return 1.0f - 2.0f / (1.0f + __expf(2.0f * x)); }
DEV void unp8(float* d, uint4 u){
  d[0]=blo(u.x); d[1]=bhi(u.x); d[2]=blo(u.y); d[3]=bhi(u.y);
  d[4]=blo(u.z); d[5]=bhi(u.z); d[6]=blo(u.w); d[7]=bhi(u.w);
}
DEV float4 unp4(u64 v){
  return make_float4(bf2f((u16)v), bf2f((u16)(v >> 16)),
                     bf2f((u16)(v >> 32)), bf2f((u16)(v >> 48)));
}
DEV float dot4(float acc, float4 w, float4 x){
  acc = fmaf(w.x,x.x,acc); acc = fmaf(w.y,x.y,acc);
  acc = fmaf(w.z,x.z,acc); acc = fmaf(w.w,x.w,acc);
  return acc;
}
DEV float fma44(float acc, float4 w0, float4 w1, float4 h0, float4 h1){
  return dot4(dot4(acc, w0, h0), w1, h1);
}
DEV float fma8(float acc, const float* w, float4 a, float4 b){
  acc = fmaf(w[0],a.x,acc); acc = fmaf(w[1],a.y,acc);
  acc = fmaf(w[2],a.z,acc); acc = fmaf(w[3],a.w,acc);
  acc = fmaf(w[4],b.x,acc); acc = fmaf(w[5],b.y,acc);
  acc = fmaf(w[6],b.z,acc); acc = fmaf(w[7],b.w,acc);
  return acc;
}
DEV float fma8p(float acc, const float* w, const float* x){
  #pragma unroll
  for (int e = 0; e < 8; ++e) acc = fmaf(w[e], x[e], acc);
  return acc;
}

// ---- agent-scope atomics (r9/r13-proven coherence rule) ----
DEV void  ast_f(float* p, float v){ __hip_atomic_store(p, v, __ATOMIC_RELAXED, __HIP_MEMORY_SCOPE_AGENT); }
DEV void  ast_u(u32* p, u32 v)    { __hip_atomic_store(p, v, __ATOMIC_RELAXED, __HIP_MEMORY_SCOPE_AGENT); }
DEV float ald_f(const float* p)   { return __hip_atomic_load((float*)p, __ATOMIC_RELAXED, __HIP_MEMORY_SCOPE_AGENT); }
DEV u64   ald_u8(const u64* p)    { return __hip_atomic_load((u64*)p,   __ATOMIC_RELAXED, __HIP_MEMORY_SCOPE_AGENT); }
DEV u32   ald_u (const u32* p)    { return __hip_atomic_load((u32*)p,   __ATOMIC_RELAXED, __HIP_MEMORY_SCOPE_AGENT); }

// Distributed grid barrier (r17/r18-proven).
DEV void grid_bar(u32* flags, int bid, int nb, u32 epoch){
  __syncthreads();
  if (threadIdx.x == 0) ast_u(&flags[bid * 32], epoch);
  if (threadIdx.x < (u32)nb) {
    while (ald_u(&flags[threadIdx.x * 32]) < epoch)
      __builtin_amdgcn_s_sleep(1);
  }
  __syncthreads();
}

// ---------- K1: gi = gather(emb, tok) @ W[:, :256]^T + bih  (bf16 out) ----
__global__ __launch_bounds__(256)
void k_embed_gemm(const int* __restrict__ tok, int Tlen,
                  const float* __restrict__ emb,
                  const float* __restrict__ W, int wstride,
                  const float* __restrict__ bias,
                  u16* __restrict__ gi)
{
  __shared__ float es[16][EE];
  const int tid = threadIdx.x;
  const int r0 = blockIdx.y * 16;
  #pragma unroll
  for (int rr = 0; rr < 16; ++rr) {
    int r = r0 + rr;
    int token = tok[(r & 31) * Tlen + (r >> 5)];
    es[rr][tid] = emb[(size_t)token * EE + tid];
  }
  __syncthreads();
  const int jl = tid & 63;
  const int rg = (tid >> 6) << 2;
  const int jbase = blockIdx.x * 256 + jl;
  float acc[4][4];
  #pragma unroll
  for (int jj = 0; jj < 4; ++jj) {
    float bv = bias[jbase + jj * 64];
    #pragma unroll
    for (int rr = 0; rr < 4; ++rr) acc[jj][rr] = bv;
  }
  const float4* w0 = (const float4*)(W + (size_t)(jbase      ) * wstride);
  const float4* w1 = (const float4*)(W + (size_t)(jbase +  64) * wstride);
  const float4* w2 = (const float4*)(W + (size_t)(jbase + 128) * wstride);
  const float4* w3 = (const float4*)(W + (size_t)(jbase + 192) * wstride);
  for (int k4 = 0; k4 < EE / 4; ++k4) {
    float4 wv0 = w0[k4], wv1 = w1[k4], wv2 = w2[k4], wv3 = w3[k4];
    #pragma unroll
    for (int rr = 0; rr < 4; ++rr) {
      float4 e = *(const float4*)&es[rg + rr][k4 * 4];
      acc[0][rr] = dot4(acc[0][rr], wv0, e);
      acc[1][rr] = dot4(acc[1][rr], wv1, e);
      acc[2][rr] = dot4(acc[2][rr], wv2, e);
      acc[3][rr] = dot4(acc[3][rr], wv3, e);
    }
  }
  #pragma unroll
  for (int rr = 0; rr < 4; ++rr)
    #pragma unroll
    for (int jj = 0; jj < 4; ++jj)
      gi[(size_t)(r0 + rg + rr) * G3 + jbase + jj * 64] = f2bf(acc[jj][rr]);
}

// ---------- K2: encoder GRU scan — 256 blocks = (b-half x 128 i-groups) --
// Block (bh, ig): b in [bh*16, +16), i in [ig*4, +4). Thread: i_l[4] x
// b_l[16] x kq[4] (k-quarter). Staging halved (16 b's), gemv halved.
__global__ __launch_bounds__(256)
void k_enc_scan(const u16* __restrict__ gi, const float* __restrict__ Whh,
                const float* __restrict__ bhh, u16* __restrict__ hring,
                u16* __restrict__ enc_outs, u32* __restrict__ flags)
{
  __shared__ float hs16[16 * HP];   // 33.0 KB (16 b's)
  __shared__ float wsl[12 * WPE];   // 24.8 KB f32
  __shared__ float h2t[4][16];
  const int tid = threadIdx.x;
  const int bid = blockIdx.x;
  const int bh = bid >> 7, ig = bid & 127;
  const int i0 = ig * 4, b0 = bh * 16;
  #pragma unroll
  for (int j = 0; j < 6; ++j) {     // stage 12 rows x 512 f32
    int f = (j * 256 + tid) * 4;
    int rowl = f >> 9, k = f & 511;
    int g = rowl >> 2, ri = rowl & 3;
    *(float4*)&wsl[rowl * WPE + k] =
      *(const float4*)(Whh + (size_t)(g * 512 + i0 + ri) * 512 + k);
  }
  const int i_l = tid >> 6, lane = tid & 63, b_l = lane >> 2, kq = lane & 3;
  const int i = i0 + i_l;
  const float* w0 = wsl + (0 * 4 + i_l) * WPE + kq * 128;
  const float* w1 = wsl + (1 * 4 + i_l) * WPE + kq * 128;
  const float* w2 = wsl + (2 * 4 + i_l) * WPE + kq * 128;
  const float bR = bhh[i], bZ = bhh[i + 512], bN = bhh[i + 1024];
  for (int t = 0; t < SS; ++t) {
    // stage h for OUR 16 b's: 2048 u64 = 8/thread
    const u64* hsrc = (const u64*)(hring + (size_t)t * 16384);
    #pragma unroll
    for (int j = 0; j < 8; ++j) {
      int idx = j * 256 + tid;
      int lb = idx >> 7, gu = idx & 127;
      u64 v = ald_u8(hsrc + (size_t)(b0 + lb) * 128 + gu);
      *(float4*)&hs16[lb * HP + gu * 4] = unp4(v);
    }
    __syncthreads();
    float aR = 0.f, aZ = 0.f, aN = 0.f;
    const float* hb = hs16 + b_l * HP + kq * 128;
    for (int k8 = 0; k8 < 16; ++k8) {
      float4 h0 = *(const float4*)&hb[k8*8], h1 = *(const float4*)&hb[k8*8+4];
      aR = fma44(aR, *(const float4*)&w0[k8*8], *(const float4*)&w0[k8*8+4], h0, h1);
      aZ = fma44(aZ, *(const float4*)&w1[k8*8], *(const float4*)&w1[k8*8+4], h0, h1);
      aN = fma44(aN, *(const float4*)&w2[k8*8], *(const float4*)&w2[k8*8+4], h0, h1);
    }
    aR += __shfl_xor(aR, 1); aR += __shfl_xor(aR, 2);
    aZ += __shfl_xor(aZ, 1); aZ += __shfl_xor(aZ, 2);
    aN += __shfl_xor(aN, 1); aN += __shfl_xor(aN, 2);
    if (kq == 0) {
      const int bg = b0 + b_l;
      const size_t g = ((size_t)t * 32 + bg) * G3;
      float r = sigf (bf2f(gi[g +        i]) + aR + bR);
      float z = sigf (bf2f(gi[g +  512 + i]) + aZ + bZ);
      float n = tanh_(bf2f(gi[g + 1024 + i]) + r * (aN + bN));
      float h2 = z * hs16[b_l * HP + i] + (1.f - z) * n;
      enc_outs[((size_t)bg * 256 + t) * 512 + i] = f2bf(h2);
      h2t[i_l][b_l] = h2;
    }
    __syncthreads();
    if (tid < 32) {    // 32 packed u32: 2 i-pairs x 16 b
      int p = tid >> 4, bl = tid & 15;
      u32 pk = (u32)f2bf(h2t[2*p][bl]) | ((u32)f2bf(h2t[2*p+1][bl]) << 16);
      ast_u((u32*)(hring + (size_t)(t + 1) * 16384)
            + (b0 + bl) * 256 + (i0 >> 1) + p, pk);
    }
    grid_bar(flags, bid, 256, (u32)(t + 1));
  }
}

// ---------- K3: enc_proj = enc_outs @ attn_W2^T + b2 ----------
__global__ __launch_bounds__(256)
void k_proj(const u16* __restrict__ A, const float* __restrict__ W,
            const float* __restrict__ bias, u16* __restrict__ Out)
{
  __shared__ float es[16][HH];
  const int tid = threadIdx.x;
  const int r0 = blockIdx.y * 16;
  #pragma unroll
  for (int j = 0; j < 4; ++j) {
    int u = j * 256 + tid;
    int row = u >> 6, k = (u & 63) * 8;
    float d[8]; unp8(d, *(const uint4*)(A + (size_t)(r0 + row) * HH + k));
    *(float4*)&es[row][k]     = make_float4(d[0],d[1],d[2],d[3]);
    *(float4*)&es[row][k + 4] = make_float4(d[4],d[5],d[6],d[7]);
  }
  __syncthreads();
  const int jl = tid & 63;
  const int rg = (tid >> 6) << 2;
  const int jbase = blockIdx.x * 256 + jl;
  float acc[4][4];
  #pragma unroll
  for (int jj = 0; jj < 4; ++jj) {
    float bv = bias[jbase + jj * 64];
    #pragma unroll
    for (int rr = 0; rr < 4; ++rr) acc[jj][rr] = bv;
  }
  const float4* w0 = (const float4*)(W + (size_t)(jbase      ) * HH);
  const float4* w1 = (const float4*)(W + (size_t)(jbase +  64) * HH);
  const float4* w2 = (const float4*)(W + (size_t)(jbase + 128) * HH);
  const float4* w3 = (const float4*)(W + (size_t)(jbase + 192) * HH);
  for (int k4 = 0; k4 < HH / 4; ++k4) {
    float4 wv0 = w0[k4], wv1 = w1[k4], wv2 = w2[k4], wv3 = w3[k4];
    #pragma unroll
    for (int rr = 0; rr < 4; ++rr) {
      float4 e = *(const float4*)&es[rg + rr][k4 * 4];
      acc[0][rr] = dot4(acc[0][rr], wv0, e);
      acc[1][rr] = dot4(acc[1][rr], wv1, e);
      acc[2][rr] = dot4(acc[2][rr], wv2, e);
      acc[3][rr] = dot4(acc[3][rr], wv3, e);
    }
  }
  #pragma unroll
  for (int rr = 0; rr < 4; ++rr)
    #pragma unroll
    for (int jj = 0; jj < 4; ++jj)
      Out[(size_t)(r0 + rg + rr) * HH + jbase + jj * 64] = f2bf(acc[jj][rr]);
}

// ---------- K4: decoder scan — b-partitioned P1/P3 (r16/r17/r18-proven) --
__global__ __launch_bounds__(256)
void k_dec_scan(const u16* __restrict__ gi, u16* __restrict__ hring,
                const float* __restrict__ W1, const float* __restrict__ b1,
                const float* __restrict__ av,
                const u16* __restrict__ enc_proj, const u16* __restrict__ enc_outs,
                const float* __restrict__ Whh, const float* __restrict__ Wih,
                const float* __restrict__ bhh,
                float* __restrict__ aring, u16* __restrict__ ctxP,
                float* __restrict__ sringP, u16* __restrict__ h2bf,
                u32* __restrict__ flags)
{
  __shared__ float hs8[8 * HP];      // 16.5 KB
  __shared__ u16  csb8[8 * CP8];     //  8.3 KB
  __shared__ u16  wlds[112 * WPD];   // 113.8 KB
  __shared__ float as_[512], vs_[512];
  __shared__ float scq[4][64], wts[64];
  __shared__ float rs[8];
  __shared__ float h2t[16][8];
  const int tid = threadIdx.x;
  const int bid = blockIdx.x;
  const int bg = bid >> 5, ig = bid & 31;
  const int b_l = tid >> 5, i_l = (tid >> 1) & 15, kh = tid & 1;
  const int i = ig * 16 + i_l;
  const int bglob = bg * 8 + b_l;
  const int pb = bid >> 2, sq = bid & 3;
  vs_[tid] = av[tid]; vs_[tid + 256] = av[tid + 256];
  for (int j = 0; j < 56; ++j) {
    int idx = j * 256 + tid;
    int row = idx >> 7, k4 = idx & 127;
    const float* src;
    if (row < 16)      src = W1  + (size_t)(ig * 16 + row) * 512 + k4 * 4;
    else if (row < 64) { int rr = row - 16; int g = rr >> 4, ii = rr & 15;
                         src = Whh + (size_t)(g * 512 + ig * 16 + ii) * 512 + k4 * 4; }
    else               { int rr = row - 64; int g = rr >> 4, ii = rr & 15;
                         src = Wih + (size_t)(g * 512 + ig * 16 + ii) * 768 + 256 + k4 * 4; }
    float4 w = *(const float4*)src;
    int f = row * WPD + k4 * 4;
    wlds[f] = f2bf(w.x); wlds[f+1] = f2bf(w.y); wlds[f+2] = f2bf(w.z); wlds[f+3] = f2bf(w.w);
  }
  const u16* w1r = wlds + (      i_l) * WPD + kh * 256;
  const u16* whr = wlds + (16  + i_l) * WPD + kh * 256;
  const u16* whz = wlds + (32  + i_l) * WPD + kh * 256;
  const u16* whn = wlds + (48  + i_l) * WPD + kh * 256;
  const u16* wir = wlds + (64  + i_l) * WPD + kh * 256;
  const u16* wiz = wlds + (80  + i_l) * WPD + kh * 256;
  const u16* win = wlds + (96  + i_l) * WPD + kh * 256;
  const float bR = bhh[i], bZ = bhh[i + 512], bN = bhh[i + 1024];
  const float b1i = b1[i];
  u32 ep = 0;
  for (int t = 0; t < TT; ++t) {
    const u64* hsrc = (const u64*)(hring + (size_t)(256 + t) * 16384);
    #pragma unroll
    for (int j = 0; j < 4; ++j) {
      int idx = j * 256 + tid;
      int lb = idx >> 7, gu = idx & 127;
      u64 v = ald_u8(hsrc + (size_t)(bg * 8 + lb) * 128 + gu);
      *(float4*)&hs8[lb * HP + gu * 4] = unp4(v);
    }
    __syncthreads();
    // ---- P1 ----
    {
      const float* hb = hs8 + b_l * HP + kh * 256;
      float acc = 0.f;
      for (int k8 = 0; k8 < 32; ++k8) {
        float wf[8]; unp8(wf, *(const uint4*)(w1r + k8 * 8));
        acc = fma8(acc, wf, *(const float4*)&hb[k8*8], *(const float4*)&hb[k8*8+4]);
      }
      acc += __shfl_xor(acc, 1);
      if (kh == 0) ast_f(&aring[(size_t)t * 16384 + bglob * 512 + i], acc + b1i);
    }
    ++ep; grid_bar(flags, bid, 128, ep);
    // ---- P2 (pb,sq): scores -> exp -> partial ctx/S ----
    {
      u64 v = ald_u8((const u64*)(aring + (size_t)t * 16384 + pb * 512) + tid);
      union { u64 q; float f[2]; } cv; cv.q = v;
      as_[2 * tid] = cv.f[0]; as_[2 * tid + 1] = cv.f[1];
    }
    __syncthreads();
    {
      const int kp = tid >> 6, s_l = tid & 63;
      const int s = sq * 64 + s_l;
      const u16* pr = enc_proj + ((size_t)pb * 256 + s) * 512 + kp * 128;
      const float* ak = as_ + kp * 128;
      const float* vk = vs_ + kp * 128;
      float acc = 0.f;
      for (int k8 = 0; k8 < 16; ++k8) {
        float d[8]; unp8(d, *(const uint4*)(pr + k8 * 8));
        #pragma unroll
        for (int e = 0; e < 8; ++e)
          acc += vk[k8 * 8 + e] * tanh_(d[e] + ak[k8 * 8 + e]);
      }
      scq[kp][s_l] = acc;
    }
    __syncthreads();
    if (tid < 64) {
      float sc = (scq[0][tid] + scq[1][tid]) + (scq[2][tid] + scq[3][tid]);
      float e = __expf(sc);          // bounded scores: no max-shift (proven r7)
      wts[tid] = e;
      float su = e;
      #pragma unroll
      for (int d = 1; d < 64; d <<= 1) su += __shfl_xor(su, d);
      if (tid == 0) ast_f(&sringP[t * 128 + sq * 32 + pb], su);
    }
    __syncthreads();
    {
      const int k0 = tid * 2;
      float c0 = 0.f, c1 = 0.f;
      const u16* eo = enc_outs + ((size_t)pb * 256 + sq * 64) * 512 + k0;
      for (int s = 0; s < 64; ++s) {
        float w = wts[s];
        u32 pair = *(const u32*)(eo + (size_t)s * 512);
        c0 = fmaf(w, blo(pair), c0);
        c1 = fmaf(w, bhi(pair), c1);
      }
      u32 pk = (u32)f2bf(c0) | ((u32)f2bf(c1) << 16);
      ast_u((u32*)(ctxP + (size_t)t * 65536 + (sq * 32 + pb) * 512 + k0), pk);
    }
    ++ep; grid_bar(flags, bid, 128, ep);
    // ---- P3: combine partials for OUR 8 b's, GRU ----
    if (tid < 8) {
      const float* sp = sringP + t * 128;
      int bq = bg * 8 + tid;
      rs[tid] = 1.f / ((ald_f(sp + bq) + ald_f(sp + 32 + bq)) +
                       (ald_f(sp + 64 + bq) + ald_f(sp + 96 + bq)));
    }
    __syncthreads();
    #pragma unroll
    for (int j = 0; j < 4; ++j) {
      int idx = j * 256 + tid;
      int lb = idx >> 7, gu = idx & 127;
      const u64* bp = (const u64*)(ctxP + (size_t)t * 65536);
      float c[4] = {0,0,0,0};
      #pragma unroll
      for (int q = 0; q < 4; ++q) {
        float4 d = unp4(ald_u8(bp + (size_t)(q * 32 + bg * 8 + lb) * 128 + gu));
        c[0] += d.x; c[1] += d.y; c[2] += d.z; c[3] += d.w;
      }
      float r = rs[lb];
      int m = gu * 4;
      *(u32*)&csb8[lb * CP8 + m]     = (u32)f2bf(c[0]*r) | ((u32)f2bf(c[1]*r) << 16);
      *(u32*)&csb8[lb * CP8 + m + 2] = (u32)f2bf(c[2]*r) | ((u32)f2bf(c[3]*r) << 16);
    }
    __syncthreads();
    {
      const float* hb = hs8 + b_l * HP + kh * 256;
      const u16*   cb = csb8 + b_l * CP8 + kh * 256;
      float hR=0.f,hZ=0.f,hN=0.f,cR=0.f,cZ=0.f,cN=0.f;
      for (int k8 = 0; k8 < 32; ++k8) {
        float4 h0 = *(const float4*)&hb[k8*8], h1 = *(const float4*)&hb[k8*8+4];
        float cf[8]; unp8(cf, *(const uint4*)(cb + k8 * 8));
        float wf[8];
        unp8(wf, *(const uint4*)(whr + k8 * 8)); hR = fma8(hR, wf, h0, h1);
        unp8(wf, *(const uint4*)(whz + k8 * 8)); hZ = fma8(hZ, wf, h0, h1);
        unp8(wf, *(const uint4*)(whn + k8 * 8)); hN = fma8(hN, wf, h0, h1);
        unp8(wf, *(const uint4*)(wir + k8 * 8)); cR = fma8p(cR, wf, cf);
        unp8(wf, *(const uint4*)(wiz + k8 * 8)); cZ = fma8p(cZ, wf, cf);
        unp8(wf, *(const uint4*)(win + k8 * 8)); cN = fma8p(cN, wf, cf);
      }
      hR += __shfl_xor(hR, 1); hZ += __shfl_xor(hZ, 1); hN += __shfl_xor(hN, 1);
      cR += __shfl_xor(cR, 1); cZ += __shfl_xor(cZ, 1); cN += __shfl_xor(cN, 1);
      if (kh == 0) {
        const size_t g = ((size_t)t * 32 + bglob) * G3;
        float r = sigf (bf2f(gi[g +        i]) + cR + hR + bR);
        float z = sigf (bf2f(gi[g +  512 + i]) + cZ + hZ + bZ);
        float n = tanh_(bf2f(gi[g + 1024 + i]) + cN + r * (hN + bN));
        float h2 = z * hs8[b_l * HP + i] + (1.f - z) * n;
        h2bf[((size_t)t * 32 + bglob) * 512 + i] = f2bf(h2);  // cross-kernel
        h2t[i_l][b_l] = h2;
      }
    }
    __syncthreads();
    if (tid < 64) {
      int p = tid >> 3, bl = tid & 7;
      u32 pk = (u32)f2bf(h2t[2*p][bl]) | ((u32)f2bf(h2t[2*p+1][bl]) << 16);
      ast_u((u32*)(hring + (size_t)(257 + t) * 16384)
            + (bg * 8 + bl) * 256 + ig * 8 + p, pk);
    }
    ++ep; grid_bar(flags, bid, 128, ep);
  }
}

// ---------- K5: fcW f32 -> bf16 (one-time) ----------
__global__ __launch_bounds__(256)
void k_cvt(const float* __restrict__ in, u16* __restrict__ out)
{
  size_t i = ((size_t)blockIdx.x * 256 + threadIdx.x) * 8;
  float4 a = *(const float4*)(in + i);
  float4 b = *(const float4*)(in + i + 4);
  union { uint4 v; u16 s[8]; } u;
  u.s[0]=f2bf(a.x); u.s[1]=f2bf(a.y); u.s[2]=f2bf(a.z); u.s[3]=f2bf(a.w);
  u.s[4]=f2bf(b.x); u.s[5]=f2bf(b.y); u.s[6]=f2bf(b.z); u.s[7]=f2bf(b.w);
  *(uint4*)(out + i) = u.v;
}

// ---------- K6: logits via bf16 MFMA (proven) ----------
__global__ __launch_bounds__(256)
void k_logits_mfma(const u16* __restrict__ A, const u16* __restrict__ Wb,
                   const float* __restrict__ bias, float* __restrict__ out)
{
  __shared__ u16 Al[64 * 512];
  const int tid = threadIdx.x;
  const int r0 = blockIdx.x * 64;
  const int v0 = blockIdx.y * 64;
  {
    const uint4* src = (const uint4*)(A + (size_t)r0 * 512);
    uint4* dst = (uint4*)Al;
    #pragma unroll
    for (int j = 0; j < 16; ++j) {
      int idx = j * 256 + tid;
      int row = idx >> 6, g = idx & 63;
      dst[(row << 6) | (g ^ (row & 7))] = src[idx];
    }
  }
  const int w  = tid >> 6, l = tid & 63;
  const int lr = l & 15,  qk = l >> 4;
  const int v  = v0 + w * 16 + lr;
  frag bfr[16];
  {
    const u16* wrow = Wb + (size_t)v * 512 + qk * 8;
    #pragma unroll
    for (int ks = 0; ks < 16; ++ks)
      bfr[ks] = *(const frag*)(wrow + ks * 32);
  }
  const float bv = bias[v];
  __syncthreads();
  f32x4v acc[4];
  #pragma unroll
  for (int mt = 0; mt < 4; ++mt) acc[mt] = (f32x4v){0.f, 0.f, 0.f, 0.f};
  #pragma unroll
  for (int ks = 0; ks < 16; ++ks) {
    #pragma unroll
    for (int mt = 0; mt < 4; ++mt) {
      const int row = mt * 16 + lr;
      const int gr  = ks * 4 + qk;
      frag a = *(const frag*)&Al[(row << 9) | ((gr ^ (row & 7)) << 3)];
      acc[mt] = __builtin_amdgcn_mfma_f32_16x16x32_bf16(a, bfr[ks], acc[mt], 0, 0, 0);
    }
  }
  #pragma unroll
  for (int mt = 0; mt < 4; ++mt)
    #pragma unroll
    for (int reg = 0; reg < 4; ++reg) {
      const int r = r0 + mt * 16 + qk * 4 + reg;
      out[(size_t)(r & 31) * 64 * VV + (size_t)(r >> 5) * VV + v] = acc[mt][reg] + bv;
    }
}

// ---------- launch ----------
extern "C" void kernel_launch(void* const* d_in, const int* in_sizes, int n_in,
                              void* d_out, int out_size, void* d_ws, size_t ws_size,
                              hipStream_t stream) {
  (void)in_sizes; (void)n_in; (void)out_size; (void)ws_size;
  const int*   src  = (const int*)d_in[0];
  const int*   tgt  = (const int*)d_in[1];
  const float* eemb = (const float*)d_in[2];
  const float* eWih = (const float*)d_in[3];
  const float* eWhh = (const float*)d_in[4];
  const float* ebih = (const float*)d_in[5];
  const float* ebhh = (const float*)d_in[6];
  const float* demb = (const float*)d_in[7];
  const float* aW1  = (const float*)d_in[8];
  const float* ab1  = (const float*)d_in[9];
  const float* aW2  = (const float*)d_in[10];
  const float* ab2  = (const float*)d_in[11];
  const float* av   = (const float*)d_in[12];
  const float* dWih = (const float*)d_in[13];
  const float* dWhh = (const float*)d_in[14];
  const float* dbih = (const float*)d_in[15];
  const float* dbhh = (const float*)d_in[16];
  const float* fcW  = (const float*)d_in[17];
  const float* fcb  = (const float*)d_in[18];
  float* out = (float*)d_out;

  // workspace carve (~71 MiB)
  float* aring   = (float*)d_ws;                 // 64x16384 f32 (4 MiB)
  float* sringP  = aring + 1048576;              // 64x128 f32 (32 KiB)
  u32*   flags   = (u32*)(sringP + 8192);        // 256x32 + 128x32 u32 (48 KiB)
  u16*  ctxP     = (u16*)(flags + 12288);        // 64x128x512 u16 (8 MiB)
  u16*  hring    = ctxP + 4194304;               // 321x16384 u16 (10.5 MiB)
  u16*  h2bf     = hring + 5259264;              // 1,048,576 u16
  u16*  gi_enc   = h2bf + 1048576;               // 12,582,912 u16
  u16*  gi_dec   = gi_enc + 12582912;            //  3,145,728 u16
  u16*  enc_outs = gi_dec + 3145728;             //  4,194,304 u16
  u16*  enc_proj = enc_outs + 4194304;           //  4,194,304 u16
  u16*  wbf      = gi_enc;  // fcW bf16 alias (dead after k_dec_scan)

  hipMemsetAsync(hring, 0, 16384 * sizeof(u16), stream);   // h0 slot (zeros)
  hipMemsetAsync(flags, 0, 12288 * sizeof(u32), stream);   // barrier flags

  k_embed_gemm<<<dim3(6, 512), 256, 0, stream>>>(src, SS, eemb, eWih, EE,  ebih, gi_enc);
  k_embed_gemm<<<dim3(6, 128), 256, 0, stream>>>(tgt, TT, demb, dWih, 768, dbih, gi_dec);

  k_enc_scan<<<256, 256, 0, stream>>>(gi_enc, eWhh, ebhh, hring, enc_outs, flags);

  k_proj<<<dim3(2, 512), 256, 0, stream>>>(enc_outs, aW2, ab2, enc_proj);

  k_dec_scan<<<128, 256, 0, stream>>>(gi_dec, hring, aW1, ab1, av,
                                      enc_proj, enc_outs, dWhh, dWih, dbhh,
                                      aring, ctxP, sringP, h2bf, flags + 8192);

  k_cvt<<<8000, 256, 0, stream>>>(fcW, wbf);

  k_logits_mfma<<<dim3(32, 500), 256, 0, stream>>>(h2bf, wbf, fcb, out);
}